// Round 2
// baseline (127.280 us; speedup 1.0000x reference)
//
#include <hip/hip_runtime.h>
#include <math.h>

// Chamfer distance, B=4, N=M=8192, D=3, fp32.
// Two one-directional NN-min passes fused into ONE kernel launch
// (direction decoded from blockIdx.z). Query points register-resident,
// reference points staged in LDS tiles; min of SQUARED distances (sqrt
// deferred to the final reduction since sqrt is monotonic). Partial mins
// across the M-split merged with atomicMin on uint-reinterpreted fp32
// (bit-pattern order == float order for non-negative floats).

constexpr int TPB = 256;        // threads per block
constexpr int NPT = 4;          // query points per thread (registers)
constexpr int PPB = TPB * NPT;  // 1024 query points per block
constexpr int MT  = 256;        // reference points per LDS tile
constexpr int MSPLIT = 32;      // blocks splitting the reference cloud

__global__ __launch_bounds__(TPB) void chamfer_nn_min(
    const float* __restrict__ A,          // [B, N, 3] input cloud
    const float* __restrict__ Bp,         // [B, M, 3] target cloud
    unsigned int* __restrict__ minA,      // [B, N] min d2 bits (over target)
    unsigned int* __restrict__ minB,      // [B, M] min d2 bits (over input)
    int N, int M, int B)
{
    const int bz  = blockIdx.z;
    const int b   = bz % B;
    const int dir = bz / B;               // 0: query=A ref=B, 1: query=B ref=A

    const float* Q = dir ? Bp : A;
    const float* R = dir ? A  : Bp;
    unsigned int* out_min = dir ? minB : minA;
    const int NQ = dir ? M : N;
    const int NR = dir ? N : M;
    const int mSlice = NR / MSPLIT;

    const int tid    = threadIdx.x;
    const int nBase  = blockIdx.x * PPB;
    const int mStart = blockIdx.y * mSlice;

    const float* qb = Q + (size_t)b * NQ * 3;
    const float* rb = R + (size_t)b * NR * 3;

    float qx[NPT], qy[NPT], qz[NPT], dmin[NPT];
#pragma unroll
    for (int k = 0; k < NPT; ++k) {
        const int n = nBase + tid + k * TPB;
        qx[k] = qb[n * 3 + 0];
        qy[k] = qb[n * 3 + 1];
        qz[k] = qb[n * 3 + 2];
        dmin[k] = 3.4e38f;
    }

    __shared__ float tgt[MT * 3];  // packed xyzxyz...

    for (int m0 = mStart; m0 < mStart + mSlice; m0 += MT) {
        __syncthreads();  // protect previous tile's readers
        const float* src = rb + (size_t)m0 * 3;
        tgt[tid          ] = src[tid          ];
        tgt[tid + TPB    ] = src[tid + TPB    ];
        tgt[tid + 2 * TPB] = src[tid + 2 * TPB];
        __syncthreads();

#pragma unroll 4
        for (int j = 0; j < MT; j += 4) {
            // 4 targets = 12 floats = 3 float4 LDS reads (16B-aligned:
            // j%4==0 -> byte offset j*12 is a multiple of 48). Uniform
            // address across the wave -> broadcast, conflict-free.
            const float4 p0 = *reinterpret_cast<const float4*>(&tgt[j * 3 + 0]);
            const float4 p1 = *reinterpret_cast<const float4*>(&tgt[j * 3 + 4]);
            const float4 p2 = *reinterpret_cast<const float4*>(&tgt[j * 3 + 8]);
            const float tx0 = p0.x, ty0 = p0.y, tz0 = p0.z;
            const float tx1 = p0.w, ty1 = p1.x, tz1 = p1.y;
            const float tx2 = p1.z, ty2 = p1.w, tz2 = p2.x;
            const float tx3 = p2.y, ty3 = p2.z, tz3 = p2.w;
#pragma unroll
            for (int k = 0; k < NPT; ++k) {
                float dx, dy, dz, d2;
                dx = qx[k] - tx0; dy = qy[k] - ty0; dz = qz[k] - tz0;
                d2 = fmaf(dz, dz, fmaf(dy, dy, dx * dx));
                dmin[k] = fminf(dmin[k], d2);
                dx = qx[k] - tx1; dy = qy[k] - ty1; dz = qz[k] - tz1;
                d2 = fmaf(dz, dz, fmaf(dy, dy, dx * dx));
                dmin[k] = fminf(dmin[k], d2);
                dx = qx[k] - tx2; dy = qy[k] - ty2; dz = qz[k] - tz2;
                d2 = fmaf(dz, dz, fmaf(dy, dy, dx * dx));
                dmin[k] = fminf(dmin[k], d2);
                dx = qx[k] - tx3; dy = qy[k] - ty3; dz = qz[k] - tz3;
                d2 = fmaf(dz, dz, fmaf(dy, dy, dx * dx));
                dmin[k] = fminf(dmin[k], d2);
            }
        }
    }

#pragma unroll
    for (int k = 0; k < NPT; ++k) {
        const int n = nBase + tid + k * TPB;
        // d2 >= 0 so fp32 bit-pattern ordering == float ordering under uint min.
        atomicMin(&out_min[(size_t)b * NQ + n], __float_as_uint(dmin[k]));
    }
}

__global__ __launch_bounds__(256) void chamfer_reduce(
    const unsigned int* __restrict__ mins, int nA, int nTotal,
    float scaleA, float scaleB, float* __restrict__ out)
{
    float s = 0.0f;
    for (int i = blockIdx.x * blockDim.x + threadIdx.x; i < nTotal;
         i += gridDim.x * blockDim.x) {
        const float d2 = fmaxf(__uint_as_float(mins[i]), 0.0f);
        s += sqrtf(d2) * (i < nA ? scaleA : scaleB);
    }
    // wave-64 tree reduce
#pragma unroll
    for (int off = 32; off > 0; off >>= 1) s += __shfl_down(s, off, 64);
    __shared__ float wsum[4];
    const int lane = threadIdx.x & 63;
    const int wid  = threadIdx.x >> 6;
    if (lane == 0) wsum[wid] = s;
    __syncthreads();
    if (threadIdx.x == 0) {
        atomicAdd(out, wsum[0] + wsum[1] + wsum[2] + wsum[3]);
    }
}

extern "C" void kernel_launch(void* const* d_in, const int* in_sizes, int n_in,
                              void* d_out, int out_size, void* d_ws, size_t ws_size,
                              hipStream_t stream) {
    const float* inp = (const float*)d_in[0];  // [B, N, 3]
    const float* tgt = (const float*)d_in[1];  // [B, M, 3]
    float* out = (float*)d_out;

    const int B = 4, D = 3;
    const int N = in_sizes[0] / (B * D);  // 8192
    const int M = in_sizes[1] / (B * D);  // 8192

    unsigned int* min_in  = (unsigned int*)d_ws;     // [B*N] min d2 over target
    unsigned int* min_tgt = min_in + (size_t)B * N;  // [B*M] min d2 over input

    // 0xFFFFFFFF == uint max == +inf sentinel for the uint-min of f32 bits.
    hipMemsetAsync(d_ws, 0xFF, (size_t)(B * N + B * M) * sizeof(unsigned int), stream);
    hipMemsetAsync(d_out, 0, sizeof(float), stream);

    // Both directions in one launch: blockIdx.z in [0, 2*B).
    dim3 grid(N / PPB, MSPLIT, 2 * B);
    chamfer_nn_min<<<grid, TPB, 0, stream>>>(inp, tgt, min_in, min_tgt, N, M, B);

    // loss = sum_b [ mean_n sqrt(min_in) + mean_m sqrt(min_tgt) ]
    chamfer_reduce<<<dim3(64), 256, 0, stream>>>(
        min_in, B * N, B * (N + M), 1.0f / N, 1.0f / M, out);
}

// Round 3
// 99.664 us; speedup vs baseline: 1.2771x; 1.2771x over previous
//
#include <hip/hip_runtime.h>
#include <math.h>

// Chamfer distance, B=4, N=M=8192, D=3, fp32.
// Dot-product formulation: d^2/2 = 0.5|q|^2 + 0.5|r|^2 - q.r
// => min over refs of d^2 <=> max over refs of t = q.r - 0.5|r|^2.
// Inner loop is 3 fma + 1 max = 4 lane-ops/pair (vs 7 for (a-b)^2 form).
// Refs staged in LDS as float4 {x, y, z, -0.5|r|^2} (4th component
// computed on the fly during staging). Query points register-resident.
// Per-slice partial result sval = max(cq - dmax, 0) >= 0 merged across the
// M-split with atomicMin on uint-reinterpreted fp32 (bit order == float
// order for non-negative floats). sqrt deferred to the final reduce.

constexpr int TPB = 256;        // threads per block
constexpr int NPT = 4;          // query points per thread (registers)
constexpr int PPB = TPB * NPT;  // 1024 query points per block
constexpr int MT  = 256;        // reference points per LDS tile
constexpr int MSPLIT = 32;      // blocks splitting the reference cloud

__global__ __launch_bounds__(TPB) void chamfer_nn_min(
    const float* __restrict__ A,          // [B, N, 3] input cloud
    const float* __restrict__ Bp,         // [B, M, 3] target cloud
    unsigned int* __restrict__ minA,      // [B, N] min d2/2 bits (over target)
    unsigned int* __restrict__ minB,      // [B, M] min d2/2 bits (over input)
    int N, int M, int B)
{
    const int bz  = blockIdx.z;
    const int b   = bz % B;
    const int dir = bz / B;               // 0: query=A ref=B, 1: query=B ref=A

    const float* Q = dir ? Bp : A;
    const float* R = dir ? A  : Bp;
    unsigned int* out_min = dir ? minB : minA;
    const int NQ = dir ? M : N;
    const int NR = dir ? N : M;
    const int mSlice = NR / MSPLIT;

    const int tid    = threadIdx.x;
    const int nBase  = blockIdx.x * PPB;
    const int mStart = blockIdx.y * mSlice;

    const float* qb = Q + (size_t)b * NQ * 3;
    const float* rb = R + (size_t)b * NR * 3;

    float qx[NPT], qy[NPT], qz[NPT], cq[NPT], dmax[NPT];
#pragma unroll
    for (int k = 0; k < NPT; ++k) {
        const int n = nBase + tid + k * TPB;
        qx[k] = qb[n * 3 + 0];
        qy[k] = qb[n * 3 + 1];
        qz[k] = qb[n * 3 + 2];
        cq[k] = 0.5f * fmaf(qz[k], qz[k], fmaf(qy[k], qy[k], qx[k] * qx[k]));
        dmax[k] = -3.4e38f;
    }

    __shared__ float4 tgt[MT];  // {x, y, z, -0.5*|r|^2}

    for (int m0 = mStart; m0 < mStart + mSlice; m0 += MT) {
        __syncthreads();  // protect previous tile's readers
        const float* src = rb + (size_t)m0 * 3;
        {
            const float rx = src[tid * 3 + 0];
            const float ry = src[tid * 3 + 1];
            const float rz = src[tid * 3 + 2];
            const float negc = -0.5f * fmaf(rz, rz, fmaf(ry, ry, rx * rx));
            tgt[tid] = make_float4(rx, ry, rz, negc);
        }
        __syncthreads();

#pragma unroll 4
        for (int j = 0; j < MT; j += 4) {
            // 4 refs = 4 float4 broadcast LDS reads (uniform address across
            // the wave -> conflict-free), amortized over NPT=4 queries:
            // 4 ds_read_b128 per 64 VALU ops.
            const float4 r0 = tgt[j + 0];
            const float4 r1 = tgt[j + 1];
            const float4 r2 = tgt[j + 2];
            const float4 r3 = tgt[j + 3];
#pragma unroll
            for (int k = 0; k < NPT; ++k) {
                float t;
                t = fmaf(qz[k], r0.z, fmaf(qy[k], r0.y, fmaf(qx[k], r0.x, r0.w)));
                dmax[k] = fmaxf(dmax[k], t);
                t = fmaf(qz[k], r1.z, fmaf(qy[k], r1.y, fmaf(qx[k], r1.x, r1.w)));
                dmax[k] = fmaxf(dmax[k], t);
                t = fmaf(qz[k], r2.z, fmaf(qy[k], r2.y, fmaf(qx[k], r2.x, r2.w)));
                dmax[k] = fmaxf(dmax[k], t);
                t = fmaf(qz[k], r3.z, fmaf(qy[k], r3.y, fmaf(qx[k], r3.x, r3.w)));
                dmax[k] = fmaxf(dmax[k], t);
            }
        }
    }

#pragma unroll
    for (int k = 0; k < NPT; ++k) {
        const int n = nBase + tid + k * TPB;
        // sval = d2/2 for this slice's best ref; clamp tiny negative rounding
        // so the uint-bit ordering of atomicMin stays valid.
        const float sval = fmaxf(cq[k] - dmax[k], 0.0f);
        atomicMin(&out_min[(size_t)b * NQ + n], __float_as_uint(sval));
    }
}

__global__ __launch_bounds__(256) void chamfer_reduce(
    const unsigned int* __restrict__ mins, int nA, int nTotal,
    float scaleA, float scaleB, float* __restrict__ out)
{
    float s = 0.0f;
    for (int i = blockIdx.x * blockDim.x + threadIdx.x; i < nTotal;
         i += gridDim.x * blockDim.x) {
        const float half_d2 = __uint_as_float(mins[i]);  // >= 0 by construction
        s += sqrtf(2.0f * half_d2) * (i < nA ? scaleA : scaleB);
    }
    // wave-64 tree reduce
#pragma unroll
    for (int off = 32; off > 0; off >>= 1) s += __shfl_down(s, off, 64);
    __shared__ float wsum[4];
    const int lane = threadIdx.x & 63;
    const int wid  = threadIdx.x >> 6;
    if (lane == 0) wsum[wid] = s;
    __syncthreads();
    if (threadIdx.x == 0) {
        atomicAdd(out, wsum[0] + wsum[1] + wsum[2] + wsum[3]);
    }
}

extern "C" void kernel_launch(void* const* d_in, const int* in_sizes, int n_in,
                              void* d_out, int out_size, void* d_ws, size_t ws_size,
                              hipStream_t stream) {
    const float* inp = (const float*)d_in[0];  // [B, N, 3]
    const float* tgt = (const float*)d_in[1];  // [B, M, 3]
    float* out = (float*)d_out;

    const int B = 4, D = 3;
    const int N = in_sizes[0] / (B * D);  // 8192
    const int M = in_sizes[1] / (B * D);  // 8192

    unsigned int* min_in  = (unsigned int*)d_ws;     // [B*N] min d2/2 over target
    unsigned int* min_tgt = min_in + (size_t)B * N;  // [B*M] min d2/2 over input

    // 0xFFFFFFFF == uint max sentinel for the uint-min of f32 bits.
    hipMemsetAsync(d_ws, 0xFF, (size_t)(B * N + B * M) * sizeof(unsigned int), stream);
    hipMemsetAsync(d_out, 0, sizeof(float), stream);

    // Both directions in one launch: blockIdx.z in [0, 2*B).
    dim3 grid(N / PPB, MSPLIT, 2 * B);
    chamfer_nn_min<<<grid, TPB, 0, stream>>>(inp, tgt, min_in, min_tgt, N, M, B);

    // loss = sum_b [ mean_n sqrt(d2) + mean_m sqrt(d2) ]
    chamfer_reduce<<<dim3(64), 256, 0, stream>>>(
        min_in, B * N, B * (N + M), 1.0f / N, 1.0f / M, out);
}

// Round 4
// 98.901 us; speedup vs baseline: 1.2869x; 1.0077x over previous
//
#include <hip/hip_runtime.h>
#include <math.h>

// Chamfer distance, B=4, N=M=8192, D=3, fp32.
// Dot-product formulation: d^2/2 = 0.5|q|^2 + 0.5|r|^2 - q.r
// => min over refs of d^2 <=> max over refs of t = q.r - 0.5|r|^2.
// Refs staged in LDS as float4 {x,y,z,-0.5|r|^2}; queries register-resident.
// NPT=8 queries/thread: 4 broadcast ds_read_b128 per 128 VALU insts.
// t0..t3 computed independently, combined with nested fmaxf pairs that clang
// fuses to v_max3_f32 -> 3.5 VALU insts per pair (12 fma + 2 max3 per
// 4 refs x 1 query). Issue floor ~= 24 us on 1024 SIMDs @ 2.4 GHz.
// Per-slice partial sval = max(cq - dmax, 0) >= 0 merged across the M-split
// with atomicMin on uint-reinterpreted fp32 (bit order == float order for
// non-negative floats). sqrt deferred to the final reduce.

constexpr int TPB = 256;        // threads per block
constexpr int NPT = 8;          // query points per thread (registers)
constexpr int PPB = TPB * NPT;  // 2048 query points per block
constexpr int MT  = 256;        // reference points per LDS tile
constexpr int MSPLIT = 32;      // blocks splitting the reference cloud

__global__ __launch_bounds__(TPB) void chamfer_nn_min(
    const float* __restrict__ A,          // [B, N, 3] input cloud
    const float* __restrict__ Bp,         // [B, M, 3] target cloud
    unsigned int* __restrict__ minA,      // [B, N] min d2/2 bits (over target)
    unsigned int* __restrict__ minB,      // [B, M] min d2/2 bits (over input)
    int N, int M, int B)
{
    const int bz  = blockIdx.z;
    const int b   = bz % B;
    const int dir = bz / B;               // 0: query=A ref=B, 1: query=B ref=A

    const float* Q = dir ? Bp : A;
    const float* R = dir ? A  : Bp;
    unsigned int* out_min = dir ? minB : minA;
    const int NQ = dir ? M : N;
    const int NR = dir ? N : M;
    const int mSlice = NR / MSPLIT;

    const int tid    = threadIdx.x;
    const int nBase  = blockIdx.x * PPB;
    const int mStart = blockIdx.y * mSlice;

    const float* qb = Q + (size_t)b * NQ * 3;
    const float* rb = R + (size_t)b * NR * 3;

    float qx[NPT], qy[NPT], qz[NPT], cq[NPT], dmax[NPT];
#pragma unroll
    for (int k = 0; k < NPT; ++k) {
        const int n = nBase + tid + k * TPB;
        qx[k] = qb[n * 3 + 0];
        qy[k] = qb[n * 3 + 1];
        qz[k] = qb[n * 3 + 2];
        cq[k] = 0.5f * fmaf(qz[k], qz[k], fmaf(qy[k], qy[k], qx[k] * qx[k]));
        dmax[k] = -3.4e38f;
    }

    __shared__ float4 tgt[MT];  // {x, y, z, -0.5*|r|^2}

    for (int m0 = mStart; m0 < mStart + mSlice; m0 += MT) {
        __syncthreads();  // protect previous tile's readers
        const float* src = rb + (size_t)m0 * 3;
        {
            const float rx = src[tid * 3 + 0];
            const float ry = src[tid * 3 + 1];
            const float rz = src[tid * 3 + 2];
            const float negc = -0.5f * fmaf(rz, rz, fmaf(ry, ry, rx * rx));
            tgt[tid] = make_float4(rx, ry, rz, negc);
        }
        __syncthreads();

#pragma unroll 2
        for (int j = 0; j < MT; j += 4) {
            // 4 refs = 4 float4 broadcast LDS reads (uniform address across
            // the wave -> conflict-free), amortized over NPT=8 queries.
            const float4 r0 = tgt[j + 0];
            const float4 r1 = tgt[j + 1];
            const float4 r2 = tgt[j + 2];
            const float4 r3 = tgt[j + 3];
#pragma unroll
            for (int k = 0; k < NPT; ++k) {
                const float t0 = fmaf(qz[k], r0.z, fmaf(qy[k], r0.y, fmaf(qx[k], r0.x, r0.w)));
                const float t1 = fmaf(qz[k], r1.z, fmaf(qy[k], r1.y, fmaf(qx[k], r1.x, r1.w)));
                const float t2 = fmaf(qz[k], r2.z, fmaf(qy[k], r2.y, fmaf(qx[k], r2.x, r2.w)));
                const float t3 = fmaf(qz[k], r3.z, fmaf(qy[k], r3.y, fmaf(qx[k], r3.x, r3.w)));
                // nested fmaxf pairs -> 2x v_max3_f32
                const float m01 = fmaxf(fmaxf(t0, t1), t2);
                dmax[k] = fmaxf(fmaxf(dmax[k], m01), t3);
            }
        }
    }

#pragma unroll
    for (int k = 0; k < NPT; ++k) {
        const int n = nBase + tid + k * TPB;
        // sval = d2/2 for this slice's best ref; clamp tiny negative rounding
        // so the uint-bit ordering of atomicMin stays valid.
        const float sval = fmaxf(cq[k] - dmax[k], 0.0f);
        atomicMin(&out_min[(size_t)b * NQ + n], __float_as_uint(sval));
    }
}

__global__ __launch_bounds__(256) void chamfer_reduce(
    const unsigned int* __restrict__ mins, int nA, int nTotal,
    float scaleA, float scaleB, float* __restrict__ out)
{
    float s = 0.0f;
    for (int i = blockIdx.x * blockDim.x + threadIdx.x; i < nTotal;
         i += gridDim.x * blockDim.x) {
        const float half_d2 = __uint_as_float(mins[i]);  // >= 0 by construction
        s += sqrtf(2.0f * half_d2) * (i < nA ? scaleA : scaleB);
    }
    // wave-64 tree reduce
#pragma unroll
    for (int off = 32; off > 0; off >>= 1) s += __shfl_down(s, off, 64);
    __shared__ float wsum[4];
    const int lane = threadIdx.x & 63;
    const int wid  = threadIdx.x >> 6;
    if (lane == 0) wsum[wid] = s;
    __syncthreads();
    if (threadIdx.x == 0) {
        atomicAdd(out, wsum[0] + wsum[1] + wsum[2] + wsum[3]);
    }
}

extern "C" void kernel_launch(void* const* d_in, const int* in_sizes, int n_in,
                              void* d_out, int out_size, void* d_ws, size_t ws_size,
                              hipStream_t stream) {
    const float* inp = (const float*)d_in[0];  // [B, N, 3]
    const float* tgt = (const float*)d_in[1];  // [B, M, 3]
    float* out = (float*)d_out;

    const int B = 4, D = 3;
    const int N = in_sizes[0] / (B * D);  // 8192
    const int M = in_sizes[1] / (B * D);  // 8192

    unsigned int* min_in  = (unsigned int*)d_ws;     // [B*N] min d2/2 over target
    unsigned int* min_tgt = min_in + (size_t)B * N;  // [B*M] min d2/2 over input

    // 0xFFFFFFFF == uint max sentinel for the uint-min of f32 bits.
    hipMemsetAsync(d_ws, 0xFF, (size_t)(B * N + B * M) * sizeof(unsigned int), stream);
    hipMemsetAsync(d_out, 0, sizeof(float), stream);

    // Both directions in one launch: blockIdx.z in [0, 2*B).
    dim3 grid(N / PPB, MSPLIT, 2 * B);
    chamfer_nn_min<<<grid, TPB, 0, stream>>>(inp, tgt, min_in, min_tgt, N, M, B);

    // loss = sum_b [ mean_n sqrt(d2) + mean_m sqrt(d2) ]
    chamfer_reduce<<<dim3(64), 256, 0, stream>>>(
        min_in, B * N, B * (N + M), 1.0f / N, 1.0f / M, out);
}